// Round 5
// baseline (1065.421 us; speedup 1.0000x reference)
//
#include <hip/hip_runtime.h>
#include <hip/hip_bf16.h>

// Problem constants (fixed): bs=4, S=1024, d_model=512, HEAD=8, D_Q=64
#define BS 4
#define SEQ 1024
#define DM 512
#define NQK 1024
#define EPS 1e-9f
#define SQRTEPS 3.16227766e-5f
#define NBLK 1024           // persistent grid: 4 blocks/CU x 256 CUs, all co-resident
#define LDA 72              // LDS leading dim (ushorts): 64 + 8 pad

typedef __attribute__((ext_vector_type(8))) short short8;   // 8 bf16
typedef __attribute__((ext_vector_type(4))) float floatx4;

__device__ __forceinline__ unsigned short f2bf(float x) {
    unsigned int u = __float_as_uint(x);
    return (unsigned short)((u + 0x7fffu + ((u >> 16) & 1u)) >> 16);
}

// Device-scope grid barrier for persistent kernel. __syncthreads drains the
// block's stores to L2 (compiler emits vmcnt(0) before s_barrier); tid0's
// __threadfence (agent scope) does the cross-XCD L2 writeback; acquire fence
// after the spin invalidates L1/L2 so post-barrier reads are fresh.
__device__ __forceinline__ void gridbar(unsigned* cnt) {
    __syncthreads();
    if (threadIdx.x == 0) {
        __threadfence();
        __hip_atomic_fetch_add(cnt, 1u, __ATOMIC_RELEASE, __HIP_MEMORY_SCOPE_AGENT);
        while (__hip_atomic_load(cnt, __ATOMIC_ACQUIRE, __HIP_MEMORY_SCOPE_AGENT) < NBLK)
            __builtin_amdgcn_s_sleep(2);
        __threadfence();
    }
    __syncthreads();
}

// Streaming constant-fill of phrasal background: n_iters x 1024 floats/block
__device__ __forceinline__ void bgwrite(float* base, int n_iters, int tid) {
    floatx4 v4 = {SQRTEPS, SQRTEPS, SQRTEPS, SQRTEPS};
    for (int j = 0; j < n_iters; ++j)
        *(floatx4*)(base + (size_t)(j * 256 + tid) * 4) = v4;
}

__global__ __launch_bounds__(256, 4) void mega_kernel(
    const float* __restrict__ ctx, const int* __restrict__ am,
    const float* __restrict__ Wq, const float* __restrict__ bq,
    const float* __restrict__ Wk, const float* __restrict__ bk,
    unsigned short* __restrict__ Xbf, unsigned short* __restrict__ Wbf,
    float* __restrict__ QK, float* __restrict__ uA, float* __restrict__ vA,
    float* __restrict__ gA, float* __restrict__ CA, unsigned* __restrict__ cnt,
    float* __restrict__ attn, float* __restrict__ phrasal)
{
    __shared__ unsigned short As[128 * LDA];   // 18432 B
    __shared__ unsigned short Bs[64 * LDA];    //  9216 B
    __shared__ double wsum[4];

    const int blk = blockIdx.x;
    const int tid = threadIdx.x;

    // ---------- Phase 1: f32->bf16 convert (blocks 0..255) | phrasal 25MB ----------
    if (blk < 256) {
        int gthr = blk * 256 + tid;            // 0..65535
        #pragma unroll
        for (int j = 0; j < 40; ++j) {
            int e = gthr + 65536 * j;          // covers 2,621,440 exactly
            if (e < 2097152) {
                Xbf[e] = f2bf(ctx[e]);
            } else {
                int e2 = e - 2097152;          // 0..524287
                float s = (e2 < 262144) ? Wq[e2] : Wk[e2 - 262144];
                Wbf[e2] = f2bf(s);
            }
        }
    } else {
        bgwrite(phrasal + (size_t)(blk - 256) * 8192, 8, tid);   // 768 blks * 32KB
    }
    gridbar(cnt + 0);

    // ---------- Phase 2: GEMM 128x64 tiles (blocks 0..511) | phrasal 67MB ----------
    if (blk < 512) {
        const int bm = blk & 31, bn = blk >> 5;     // 32 x 16 tiles
        const int wave = tid >> 6, lane = tid & 63;
        const int lr = lane & 15, kg = lane >> 4;
        const unsigned short* Xb = Xbf + (size_t)(bm * 128) * DM;
        const unsigned short* Wb = Wbf + (size_t)(bn * 64) * DM;

        floatx4 acc[2][4] = {};
        for (int k0 = 0; k0 < DM; k0 += 64) {
            uint4 va[4], vb[2];
            #pragma unroll
            for (int p = 0; p < 4; ++p) {           // A: 128 rows x 8 chunks
                int c = tid + p * 256, row = c >> 3, kc = (c & 7) << 3;
                va[p] = *(const uint4*)(Xb + (size_t)row * DM + k0 + kc);
            }
            #pragma unroll
            for (int p = 0; p < 2; ++p) {           // B: 64 rows x 8 chunks
                int c = tid + p * 256, row = c >> 3, kc = (c & 7) << 3;
                vb[p] = *(const uint4*)(Wb + (size_t)row * DM + k0 + kc);
            }
            __syncthreads();
            #pragma unroll
            for (int p = 0; p < 4; ++p) {
                int c = tid + p * 256, row = c >> 3, kc = (c & 7) << 3;
                *(uint4*)(As + row * LDA + kc) = va[p];
            }
            #pragma unroll
            for (int p = 0; p < 2; ++p) {
                int c = tid + p * 256, row = c >> 3, kc = (c & 7) << 3;
                *(uint4*)(Bs + row * LDA + kc) = vb[p];
            }
            __syncthreads();
            #pragma unroll
            for (int ks = 0; ks < 2; ++ks) {
                short8 a[2], b[4];
                #pragma unroll
                for (int mi = 0; mi < 2; ++mi)
                    a[mi] = *(const short8*)(As + (wave * 32 + mi * 16 + lr) * LDA + ks * 32 + kg * 8);
                #pragma unroll
                for (int ni = 0; ni < 4; ++ni)
                    b[ni] = *(const short8*)(Bs + (ni * 16 + lr) * LDA + ks * 32 + kg * 8);
                #pragma unroll
                for (int mi = 0; mi < 2; ++mi)
                    #pragma unroll
                    for (int ni = 0; ni < 4; ++ni)
                        acc[mi][ni] = __builtin_amdgcn_mfma_f32_16x16x32_bf16(
                            a[mi], b[ni], acc[mi][ni], 0, 0, 0);
            }
        }
        #pragma unroll
        for (int mi = 0; mi < 2; ++mi) {
            #pragma unroll
            for (int ni = 0; ni < 4; ++ni) {
                int n = bn * 64 + ni * 16 + lr;
                float bias = (n < DM) ? bq[n] : bk[n - DM];
                #pragma unroll
                for (int r = 0; r < 4; ++r) {
                    int m = bm * 128 + wave * 32 + mi * 16 + kg * 4 + r;
                    QK[(size_t)m * NQK + n] = acc[mi][ni][r] + bias;
                }
            }
        }
    } else {
        bgwrite(phrasal + 6291456 + (size_t)(blk - 512) * 32768, 32, tid); // 512*128KB
    }
    gridbar(cnt + 1);

    // ---------- Phase 3: neighbor dots (blocks 0..767) | phrasal 25MB ----------
    if (blk < 768) {
        const int wv = tid >> 6, lane = tid & 63;
        const int gwv = blk * 4 + wv;               // 0..3071
        for (int gw = gwv; gw < 32768; gw += 3072) {
            int bh = gw >> 10, i = gw & 1023;
            int b = bh >> 3, h = bh & 7;
            float u = 0.f, v = 0.f;
            if (i < SEQ - 1) {
                const float* r0 = QK + (size_t)(b * SEQ + i) * NQK;
                const float* r1 = r0 + NQK;
                float qi  = r0[h * 64 + lane];
                float ki  = r0[DM + h * 64 + lane];
                float qi1 = r1[h * 64 + lane];
                float ki1 = r1[DM + h * 64 + lane];
                float pu = qi * ki1, pv = qi1 * ki;
                #pragma unroll
                for (int m = 1; m < 64; m <<= 1) {
                    pu += __shfl_xor(pu, m);
                    pv += __shfl_xor(pv, m);
                }
                u = pu * (1.0f / DM);
                v = pv * (1.0f / DM);
            }
            if (lane == 0) { uA[gw] = u; vA[gw] = v; }
        }
    } else {
        bgwrite(phrasal + 23068672 + (size_t)(blk - 768) * 24576, 24, tid); // 256*96KB
    }
    gridbar(cnt + 2);

    // ---------- Phase 4: g + exclusive log-scan (blocks 0..31) | phrasal 17MB ----------
    if (blk < 32) {
        const int bh = blk, b = bh >> 3;
        const int i0 = tid * 4;
        floatx4 u4 = *(const floatx4*)(uA + bh * SEQ + i0);
        floatx4 v4 = *(const floatx4*)(vA + bh * SEQ + i0);
        float vm1f = (i0 > 0) ? vA[bh * SEQ + i0 - 1] : 0.f;
        float up1l = (i0 + 4 < SEQ) ? uA[bh * SEQ + i0 + 4] : 0.f;
        const int* amb = am + b * SEQ;

        floatx4 g4;
        double pref[4], tsum = 0.0;
        #pragma unroll
        for (int j = 0; j < 4; ++j) {
            int i = i0 + j;
            float g = 0.f;
            if (i < SEQ - 1) {
                float u = u4[j], vv = v4[j];
                float vm1 = (j == 0) ? vm1f : v4[j - 1];
                float up1 = (j == 3) ? up1l : u4[j + 1];
                int mL = (i > 0) ? amb[i - 1] : 0;
                int mR = amb[i + 1];
                float s_up = mR ? (mL ? 1.f / (1.f + expf(vm1 - u)) : 1.f) : 0.f;
                int mL2 = amb[i];
                int mR2 = (i + 2 < SEQ) ? amb[i + 2] : 0;
                float s_dn = mL2 ? (mR2 ? 1.f / (1.f + expf(up1 - vv)) : 1.f) : 0.f;
                g = sqrtf(s_up * s_dn + EPS);
            }
            g4[j] = g;
            float L = (i < SEQ - 1) ? logf(g + EPS) : 0.f;
            pref[j] = tsum;                 // exclusive within-thread prefix
            tsum += (double)L;
        }
        double x = tsum;
        const int lane = tid & 63, wvv = tid >> 6;
        #pragma unroll
        for (int off = 1; off < 64; off <<= 1) {
            double s = __shfl_up(x, off);
            if (lane >= off) x += s;
        }
        if (lane == 63) wsum[wvv] = x;
        __syncthreads();
        double woff = 0.0;
        for (int w = 0; w < wvv; ++w) woff += wsum[w];
        double ex = woff + x - tsum;        // exclusive prefix at i0
        floatx4 C4;
        #pragma unroll
        for (int j = 0; j < 4; ++j) C4[j] = (float)(ex + pref[j]);
        *(floatx4*)(CA + bh * SEQ + i0) = C4;
        *(floatx4*)(gA + bh * SEQ + i0) = g4;
    } else if (blk < 544) {
        bgwrite(phrasal + 29360128 + (size_t)(blk - 32) * 8192, 8, tid);  // 512*32KB
    }
    gridbar(cnt + 3);

    // ---------- Phase 5: attn fill (all 1024 blocks, 32 rows each) + fixups ----------
    {
        const int bh = blk >> 5;
        floatx4 c4 = *(const floatx4*)(CA + bh * SEQ + tid * 4);
        const float* gb = gA + bh * SEQ;
        for (int rr = 0; rr < 32; ++rr) {
            int row = blk * 32 + rr;
            int i = row & 1023;
            float Ci = CA[row];
            floatx4 av;
            #pragma unroll
            for (int j = 0; j < 4; ++j) {
                int k = tid * 4 + j;
                float d = (k > i) ? (c4[j] - Ci) : (Ci - c4[j]);
                av[j] = (k == i) ? SQRTEPS : (__expf(d) + EPS);
            }
            *(floatx4*)(attn + (size_t)row * SEQ + tid * 4) = av;
            if (tid == 0 && i > 0)
                phrasal[(size_t)row * SEQ + i - 1] = gb[i - 1];
            if (tid == 1 && i < SEQ - 1)
                phrasal[(size_t)row * SEQ + i + 1] = gb[i];
        }
    }
}

// ---------------------------------------------------------------------------
extern "C" void kernel_launch(void* const* d_in, const int* in_sizes, int n_in,
                              void* d_out, int out_size, void* d_ws, size_t ws_size,
                              hipStream_t stream) {
    const float* ctx = (const float*)d_in[0];
    const int*   am  = (const int*)d_in[1];
    const float* Wq  = (const float*)d_in[2];
    const float* bq  = (const float*)d_in[3];
    const float* Wk  = (const float*)d_in[4];
    const float* bk  = (const float*)d_in[5];
    float* out = (float*)d_out;

    char* ws = (char*)d_ws;
    unsigned short* Xbf = (unsigned short*)(ws);                 //  4 MiB
    unsigned short* Wbf = (unsigned short*)(ws + 4194304);       //  1 MiB
    float*          QK  = (float*)(ws + 5242880);                // 16 MiB
    float*          uA  = (float*)(ws + 22020096);               // 128 KiB
    float*          vA  = (float*)(ws + 22151168);               // 128 KiB
    float*          gA  = (float*)(ws + 22282240);               // 128 KiB
    float*          CA  = (float*)(ws + 22413312);               // 128 KiB
    unsigned*       cnt = (unsigned*)(ws + 22544384);            // 16 B barrier ctrs

    float* attn_out    = out;
    float* phrasal_out = out + (size_t)BS * 8 * SEQ * SEQ;

    hipMemsetAsync(cnt, 0, 16, stream);   // barrier counters (ws is 0xAA-poisoned)
    mega_kernel<<<dim3(NBLK), 256, 0, stream>>>(
        ctx, am, Wq, bq, Wk, bk, Xbf, Wbf, QK, uA, vA, gA, CA, cnt,
        attn_out, phrasal_out);
}

// Round 6
// 617.640 us; speedup vs baseline: 1.7250x; 1.7250x over previous
//
#include <hip/hip_runtime.h>
#include <hip/hip_bf16.h>

// Problem constants (fixed): bs=4, S=1024, d_model=512, HEAD=8, D_Q=64
#define BS 4
#define SEQ 1024
#define DM 512
#define NQK 1024
#define EPS 1e-9f
#define SQRTEPS 3.16227766e-5f
#define NBLK 1024           // persistent grid: 4 blocks/CU x 256 CUs, all co-resident
#define LDA 72              // LDS leading dim (ushorts): 64 + 8 pad
#define NGROUP 64           // barrier release tree: 64 leaders, 16 blocks/group

typedef __attribute__((ext_vector_type(8))) short short8;   // 8 bf16
typedef __attribute__((ext_vector_type(4))) float floatx4;

__device__ __forceinline__ unsigned short f2bf(float x) {
    unsigned int u = __float_as_uint(x);
    return (unsigned short)((u + 0x7fffu + ((u >> 16) & 1u)) >> 16);
}

// Two-level grid barrier (persistent kernel, NBLK co-resident blocks).
// Control layout in cnt[] (unsigned words, 64 B spacing to avoid line sharing):
//   root[b]    = cnt[b*16]
//   flag[b][g] = cnt[64 + b*1024 + g*16]
// Arrive: every block tid0 fetch_add(root, RELEASE/AGENT) — drains + writebacks
// its stores. Release: leaders (blk<64) poll root RELAXED with ~0.4us sleep
// (no acquire-invalidate side effects, ~150 polls/us total), fence, set group
// flag; 960 waiters poll their flag (16 spinners/line). One threadfence on
// exit = acquire. R5 lesson: 1024 ACQUIRE-spinners at 50ns period congested
// the fabric to 6% HBM BW.
__device__ __forceinline__ void gridbar(unsigned* cnt, int b, int blk) {
    __syncthreads();
    if (threadIdx.x == 0) {
        unsigned* root = cnt + b * 16;
        __hip_atomic_fetch_add(root, 1u, __ATOMIC_RELEASE, __HIP_MEMORY_SCOPE_AGENT);
        if (blk < NGROUP) {
            while (__hip_atomic_load(root, __ATOMIC_RELAXED, __HIP_MEMORY_SCOPE_AGENT) < NBLK)
                __builtin_amdgcn_s_sleep(16);
            __threadfence();
            unsigned* flag = cnt + 64 + b * 1024 + blk * 16;
            __hip_atomic_store(flag, 1u, __ATOMIC_RELEASE, __HIP_MEMORY_SCOPE_AGENT);
        } else {
            unsigned* flag = cnt + 64 + b * 1024 + (blk >> 4) * 16;
            while (__hip_atomic_load(flag, __ATOMIC_RELAXED, __HIP_MEMORY_SCOPE_AGENT) == 0u)
                __builtin_amdgcn_s_sleep(16);
            __threadfence();
        }
    }
    __syncthreads();
}

// Streaming constant-fill of phrasal background: n_iters x 1024 floats/block
__device__ __forceinline__ void bgwrite(float* base, int n_iters, int tid) {
    floatx4 v4 = {SQRTEPS, SQRTEPS, SQRTEPS, SQRTEPS};
    for (int j = 0; j < n_iters; ++j)
        *(floatx4*)(base + (size_t)(j * 256 + tid) * 4) = v4;
}

__global__ __launch_bounds__(256, 4) void mega_kernel(
    const float* __restrict__ ctx, const int* __restrict__ am,
    const float* __restrict__ Wq, const float* __restrict__ bq,
    const float* __restrict__ Wk, const float* __restrict__ bk,
    unsigned short* __restrict__ Xbf, unsigned short* __restrict__ Wbf,
    float* __restrict__ QK, float* __restrict__ uA, float* __restrict__ vA,
    float* __restrict__ gA, float* __restrict__ CA, unsigned* __restrict__ cnt,
    float* __restrict__ attn, float* __restrict__ phrasal)
{
    __shared__ unsigned short As[128 * LDA];   // 18432 B
    __shared__ unsigned short Bs[64 * LDA];    //  9216 B
    __shared__ double wsum[4];

    const int blk = blockIdx.x;
    const int tid = threadIdx.x;

    // ---------- Phase 1: f32->bf16 convert (blocks 0..255) | phrasal 25MB ----------
    if (blk < 256) {
        int gthr = blk * 256 + tid;            // 0..65535
        #pragma unroll
        for (int j = 0; j < 40; ++j) {
            int e = gthr + 65536 * j;          // covers 2,621,440 exactly
            if (e < 2097152) {
                Xbf[e] = f2bf(ctx[e]);
            } else {
                int e2 = e - 2097152;          // 0..524287
                float s = (e2 < 262144) ? Wq[e2] : Wk[e2 - 262144];
                Wbf[e2] = f2bf(s);
            }
        }
    } else {
        bgwrite(phrasal + (size_t)(blk - 256) * 8192, 8, tid);   // 768 blks * 32KB
    }
    gridbar(cnt, 0, blk);

    // ---------- Phase 2: GEMM 128x64 tiles (blocks 0..511) | phrasal 67MB ----------
    if (blk < 512) {
        const int bm = blk & 31, bn = blk >> 5;     // 32 x 16 tiles
        const int wave = tid >> 6, lane = tid & 63;
        const int lr = lane & 15, kg = lane >> 4;
        const unsigned short* Xb = Xbf + (size_t)(bm * 128) * DM;
        const unsigned short* Wb = Wbf + (size_t)(bn * 64) * DM;

        floatx4 acc[2][4] = {};
        for (int k0 = 0; k0 < DM; k0 += 64) {
            uint4 va[4], vb[2];
            #pragma unroll
            for (int p = 0; p < 4; ++p) {           // A: 128 rows x 8 chunks
                int c = tid + p * 256, row = c >> 3, kc = (c & 7) << 3;
                va[p] = *(const uint4*)(Xb + (size_t)row * DM + k0 + kc);
            }
            #pragma unroll
            for (int p = 0; p < 2; ++p) {           // B: 64 rows x 8 chunks
                int c = tid + p * 256, row = c >> 3, kc = (c & 7) << 3;
                vb[p] = *(const uint4*)(Wb + (size_t)row * DM + k0 + kc);
            }
            __syncthreads();
            #pragma unroll
            for (int p = 0; p < 4; ++p) {
                int c = tid + p * 256, row = c >> 3, kc = (c & 7) << 3;
                *(uint4*)(As + row * LDA + kc) = va[p];
            }
            #pragma unroll
            for (int p = 0; p < 2; ++p) {
                int c = tid + p * 256, row = c >> 3, kc = (c & 7) << 3;
                *(uint4*)(Bs + row * LDA + kc) = vb[p];
            }
            __syncthreads();
            #pragma unroll
            for (int ks = 0; ks < 2; ++ks) {
                short8 a[2], b[4];
                #pragma unroll
                for (int mi = 0; mi < 2; ++mi)
                    a[mi] = *(const short8*)(As + (wave * 32 + mi * 16 + lr) * LDA + ks * 32 + kg * 8);
                #pragma unroll
                for (int ni = 0; ni < 4; ++ni)
                    b[ni] = *(const short8*)(Bs + (ni * 16 + lr) * LDA + ks * 32 + kg * 8);
                #pragma unroll
                for (int mi = 0; mi < 2; ++mi)
                    #pragma unroll
                    for (int ni = 0; ni < 4; ++ni)
                        acc[mi][ni] = __builtin_amdgcn_mfma_f32_16x16x32_bf16(
                            a[mi], b[ni], acc[mi][ni], 0, 0, 0);
            }
        }
        #pragma unroll
        for (int mi = 0; mi < 2; ++mi) {
            #pragma unroll
            for (int ni = 0; ni < 4; ++ni) {
                int n = bn * 64 + ni * 16 + lr;
                float bias = (n < DM) ? bq[n] : bk[n - DM];
                #pragma unroll
                for (int r = 0; r < 4; ++r) {
                    int m = bm * 128 + wave * 32 + mi * 16 + kg * 4 + r;
                    QK[(size_t)m * NQK + n] = acc[mi][ni][r] + bias;
                }
            }
        }
    } else {
        bgwrite(phrasal + 6291456 + (size_t)(blk - 512) * 32768, 32, tid); // 512*128KB
    }
    gridbar(cnt, 1, blk);

    // ---------- Phase 3: neighbor dots (blocks 0..767) | phrasal 25MB ----------
    if (blk < 768) {
        const int wv = tid >> 6, lane = tid & 63;
        const int gwv = blk * 4 + wv;               // 0..3071
        for (int gw = gwv; gw < 32768; gw += 3072) {
            int bh = gw >> 10, i = gw & 1023;
            int b = bh >> 3, h = bh & 7;
            float u = 0.f, v = 0.f;
            if (i < SEQ - 1) {
                const float* r0 = QK + (size_t)(b * SEQ + i) * NQK;
                const float* r1 = r0 + NQK;
                float qi  = r0[h * 64 + lane];
                float ki  = r0[DM + h * 64 + lane];
                float qi1 = r1[h * 64 + lane];
                float ki1 = r1[DM + h * 64 + lane];
                float pu = qi * ki1, pv = qi1 * ki;
                #pragma unroll
                for (int m = 1; m < 64; m <<= 1) {
                    pu += __shfl_xor(pu, m);
                    pv += __shfl_xor(pv, m);
                }
                u = pu * (1.0f / DM);
                v = pv * (1.0f / DM);
            }
            if (lane == 0) { uA[gw] = u; vA[gw] = v; }
        }
    } else {
        bgwrite(phrasal + 23068672 + (size_t)(blk - 768) * 24576, 24, tid); // 256*96KB
    }
    gridbar(cnt, 2, blk);

    // ---------- Phase 4: g + exclusive log-scan (blocks 0..31) | phrasal 17MB ----------
    if (blk < 32) {
        const int bh = blk, b = bh >> 3;
        const int i0 = tid * 4;
        floatx4 u4 = *(const floatx4*)(uA + bh * SEQ + i0);
        floatx4 v4 = *(const floatx4*)(vA + bh * SEQ + i0);
        float vm1f = (i0 > 0) ? vA[bh * SEQ + i0 - 1] : 0.f;
        float up1l = (i0 + 4 < SEQ) ? uA[bh * SEQ + i0 + 4] : 0.f;
        const int* amb = am + b * SEQ;

        floatx4 g4;
        double pref[4], tsum = 0.0;
        #pragma unroll
        for (int j = 0; j < 4; ++j) {
            int i = i0 + j;
            float g = 0.f;
            if (i < SEQ - 1) {
                float u = u4[j], vv = v4[j];
                float vm1 = (j == 0) ? vm1f : v4[j - 1];
                float up1 = (j == 3) ? up1l : u4[j + 1];
                int mL = (i > 0) ? amb[i - 1] : 0;
                int mR = amb[i + 1];
                float s_up = mR ? (mL ? 1.f / (1.f + expf(vm1 - u)) : 1.f) : 0.f;
                int mL2 = amb[i];
                int mR2 = (i + 2 < SEQ) ? amb[i + 2] : 0;
                float s_dn = mL2 ? (mR2 ? 1.f / (1.f + expf(up1 - vv)) : 1.f) : 0.f;
                g = sqrtf(s_up * s_dn + EPS);
            }
            g4[j] = g;
            float L = (i < SEQ - 1) ? logf(g + EPS) : 0.f;
            pref[j] = tsum;                 // exclusive within-thread prefix
            tsum += (double)L;
        }
        double x = tsum;
        const int lane = tid & 63, wvv = tid >> 6;
        #pragma unroll
        for (int off = 1; off < 64; off <<= 1) {
            double s = __shfl_up(x, off);
            if (lane >= off) x += s;
        }
        if (lane == 63) wsum[wvv] = x;
        __syncthreads();
        double woff = 0.0;
        for (int w = 0; w < wvv; ++w) woff += wsum[w];
        double ex = woff + x - tsum;        // exclusive prefix at i0
        floatx4 C4;
        #pragma unroll
        for (int j = 0; j < 4; ++j) C4[j] = (float)(ex + pref[j]);
        *(floatx4*)(CA + bh * SEQ + i0) = C4;
        *(floatx4*)(gA + bh * SEQ + i0) = g4;
    } else if (blk < 544) {
        bgwrite(phrasal + 29360128 + (size_t)(blk - 32) * 8192, 8, tid);  // 512*32KB
    }
    gridbar(cnt, 3, blk);

    // ---------- Phase 5: attn fill (all 1024 blocks, 32 rows each) + fixups ----------
    {
        const int bh = blk >> 5;
        floatx4 c4 = *(const floatx4*)(CA + bh * SEQ + tid * 4);
        const float* gb = gA + bh * SEQ;
        for (int rr = 0; rr < 32; ++rr) {
            int row = blk * 32 + rr;
            int i = row & 1023;
            float Ci = CA[row];
            floatx4 av;
            #pragma unroll
            for (int j = 0; j < 4; ++j) {
                int k = tid * 4 + j;
                float d = (k > i) ? (c4[j] - Ci) : (Ci - c4[j]);
                av[j] = (k == i) ? SQRTEPS : (__expf(d) + EPS);
            }
            *(floatx4*)(attn + (size_t)row * SEQ + tid * 4) = av;
            if (tid == 0 && i > 0)
                phrasal[(size_t)row * SEQ + i - 1] = gb[i - 1];
            if (tid == 1 && i < SEQ - 1)
                phrasal[(size_t)row * SEQ + i + 1] = gb[i];
        }
    }
}

// ---------------------------------------------------------------------------
extern "C" void kernel_launch(void* const* d_in, const int* in_sizes, int n_in,
                              void* d_out, int out_size, void* d_ws, size_t ws_size,
                              hipStream_t stream) {
    const float* ctx = (const float*)d_in[0];
    const int*   am  = (const int*)d_in[1];
    const float* Wq  = (const float*)d_in[2];
    const float* bq  = (const float*)d_in[3];
    const float* Wk  = (const float*)d_in[4];
    const float* bk  = (const float*)d_in[5];
    float* out = (float*)d_out;

    char* ws = (char*)d_ws;
    unsigned short* Xbf = (unsigned short*)(ws);                 //  4 MiB
    unsigned short* Wbf = (unsigned short*)(ws + 4194304);       //  1 MiB
    float*          QK  = (float*)(ws + 5242880);                // 16 MiB
    float*          uA  = (float*)(ws + 22020096);               // 128 KiB
    float*          vA  = (float*)(ws + 22151168);               // 128 KiB
    float*          gA  = (float*)(ws + 22282240);               // 128 KiB
    float*          CA  = (float*)(ws + 22413312);               // 128 KiB
    unsigned*       cnt = (unsigned*)(ws + 22544384);            // barrier control

    float* attn_out    = out;
    float* phrasal_out = out + (size_t)BS * 8 * SEQ * SEQ;

    // barrier control area: 4 roots (64B apart) + 4x64 flags (64B apart) < 20KB
    hipMemsetAsync(cnt, 0, 20480, stream);
    mega_kernel<<<dim3(NBLK), 256, 0, stream>>>(
        ctx, am, Wq, bq, Wk, bk, Xbf, Wbf, QK, uA, vA, gA, CA, cnt,
        attn_out, phrasal_out);
}

// Round 7
// 290.132 us; speedup vs baseline: 3.6722x; 2.1288x over previous
//
#include <hip/hip_runtime.h>
#include <hip/hip_bf16.h>

// Problem constants (fixed): bs=4, S=1024, d_model=512, HEAD=8, D_Q=64
#define BS 4
#define SEQ 1024
#define DM 512
#define EPS 1e-9f
#define SQRTEPS 3.16227766e-5f

typedef __attribute__((ext_vector_type(8))) short short8;   // 8 bf16
typedef __attribute__((ext_vector_type(4))) float floatx4;

__device__ __forceinline__ unsigned short f2bf(float x) {
    unsigned int u = __float_as_uint(x);
    return (unsigned short)((u + 0x7fffu + ((u >> 16) & 1u)) >> 16);
}

// Streaming constant-fill of phrasal background: n_iters x (nthr x 4) floats
__device__ __forceinline__ void bgwrite(float* base, int n_iters, int tid, int nthr) {
    floatx4 v4 = {SQRTEPS, SQRTEPS, SQRTEPS, SQRTEPS};
    for (int j = 0; j < n_iters; ++j)
        *(floatx4*)(base + (size_t)(j * nthr + tid) * 4) = v4;
}

// ---------------------------------------------------------------------------
// Kernel 1: f32->bf16 convert (blocks 0..255, float4-vectorized) + 768 bg
// writer blocks (24 MB phrasal background).
// ---------------------------------------------------------------------------
__global__ __launch_bounds__(256) void convert_kernel(
    const float* __restrict__ ctx, const float* __restrict__ Wq,
    const float* __restrict__ Wk, unsigned short* __restrict__ Xbf,
    unsigned short* __restrict__ Wbf, float* __restrict__ phrasal)
{
    const int blk = blockIdx.x, tid = threadIdx.x;
    if (blk >= 256) {
        bgwrite(phrasal + (size_t)(blk - 256) * 8192, 8, tid, 256);  // chunks 0..767
        return;
    }
    int gthr = blk * 256 + tid;              // 0..65535
    #pragma unroll
    for (int j = 0; j < 10; ++j) {
        int e4 = gthr + 65536 * j;           // float4 index, 655360 total
        int e  = e4 * 4;
        floatx4 s;
        if (e < 2097152) {
            s = *(const floatx4*)(ctx + e);
        } else {
            int e2 = e - 2097152;            // 0..524287
            s = (e2 < 262144) ? *(const floatx4*)(Wq + e2)
                              : *(const floatx4*)(Wk + e2 - 262144);
        }
        ushort2 lo = {f2bf(s.x), f2bf(s.y)}, hi = {f2bf(s.z), f2bf(s.w)};
        unsigned short* dst = (e < 2097152) ? (Xbf + e) : (Wbf + e - 2097152);
        *(ushort2*)dst = lo;
        *(ushort2*)(dst + 2) = hi;
    }
}

// ---------------------------------------------------------------------------
// Kernel 2: fused projection + neighbor dots. 512 compute blocks =
// (row-tile rt 0..63) x (head h 0..7). Each computes q,k tiles [64x64]
// (bias included), then the 63 in-tile neighbor dots:
//   u[i]=q_i.k_{i+1}/512, v[i]=q_{i+1}.k_i/512  for i = rt*64 + p, p<63.
// Boundary rows (0 and 63) exported to edge buffers for gscan.
// No QK matrix is ever materialized. +2048 bg writer blocks (64 MB).
// ---------------------------------------------------------------------------
#define NGEMM 512
#define LDW 72     // staging stride (ushorts)
#define LDQ 65     // qS/kS stride (floats)

__global__ __launch_bounds__(256) void gemmdot_kernel(
    const unsigned short* __restrict__ Xbf, const unsigned short* __restrict__ Wbf,
    const float* __restrict__ bq, const float* __restrict__ bk,
    float* __restrict__ uA, float* __restrict__ vA,
    float* __restrict__ qF, float* __restrict__ kF,
    float* __restrict__ qL, float* __restrict__ kL,
    float* __restrict__ phrasal)
{
    __shared__ char smem[2 * 64 * LDQ * 4];            // 33280 B (union)
    unsigned short* Xs  = (unsigned short*)smem;       // 64 x LDW
    unsigned short* Wqs = Xs + 64 * LDW;
    unsigned short* Wks = Wqs + 64 * LDW;
    float* qS = (float*)smem;                          // 64 x LDQ (overlaps staging)
    float* kS = qS + 64 * LDQ;

    const int blk = blockIdx.x, tid = threadIdx.x;
    if (blk >= NGEMM) {
        bgwrite(phrasal + (size_t)(768 + blk - NGEMM) * 8192, 8, tid, 256); // 768..2815
        return;
    }

    const int rt = blk >> 3, h = blk & 7;
    const int wv = tid >> 6, lane = tid & 63;
    const int lr = lane & 15, kg = lane >> 4;

    // staging: chunk c covers row=c>>3, kc=(c&7)*8; thread handles c=tid, tid+256
    const int r0 = tid >> 3, kc0 = (tid & 7) << 3;
    const unsigned short* Xb  = Xbf + (size_t)(rt * 64) * DM;
    const unsigned short* Wqb = Wbf + (size_t)(h * 64) * DM;
    const unsigned short* Wkb = Wbf + 262144 + (size_t)(h * 64) * DM;

    floatx4 acc_q[4] = {}, acc_k[4] = {};

    for (int k0 = 0; k0 < DM; k0 += 64) {
        uint4 x0  = *(const uint4*)(Xb  + (size_t)r0 * DM + k0 + kc0);
        uint4 x1  = *(const uint4*)(Xb  + (size_t)(r0 + 32) * DM + k0 + kc0);
        uint4 wq0 = *(const uint4*)(Wqb + (size_t)r0 * DM + k0 + kc0);
        uint4 wq1 = *(const uint4*)(Wqb + (size_t)(r0 + 32) * DM + k0 + kc0);
        uint4 wk0 = *(const uint4*)(Wkb + (size_t)r0 * DM + k0 + kc0);
        uint4 wk1 = *(const uint4*)(Wkb + (size_t)(r0 + 32) * DM + k0 + kc0);
        __syncthreads();
        *(uint4*)(Xs  + r0 * LDW + kc0)        = x0;
        *(uint4*)(Xs  + (r0 + 32) * LDW + kc0) = x1;
        *(uint4*)(Wqs + r0 * LDW + kc0)        = wq0;
        *(uint4*)(Wqs + (r0 + 32) * LDW + kc0) = wq1;
        *(uint4*)(Wks + r0 * LDW + kc0)        = wk0;
        *(uint4*)(Wks + (r0 + 32) * LDW + kc0) = wk1;
        __syncthreads();
        #pragma unroll
        for (int ks = 0; ks < 2; ++ks) {
            short8 a = *(const short8*)(Xs + (wv * 16 + lr) * LDW + ks * 32 + kg * 8);
            #pragma unroll
            for (int ni = 0; ni < 4; ++ni) {
                short8 bqf = *(const short8*)(Wqs + (ni * 16 + lr) * LDW + ks * 32 + kg * 8);
                acc_q[ni] = __builtin_amdgcn_mfma_f32_16x16x32_bf16(a, bqf, acc_q[ni], 0, 0, 0);
                short8 bkf = *(const short8*)(Wks + (ni * 16 + lr) * LDW + ks * 32 + kg * 8);
                acc_k[ni] = __builtin_amdgcn_mfma_f32_16x16x32_bf16(a, bkf, acc_k[ni], 0, 0, 0);
            }
        }
    }

    // epilogue: C/D layout col = lane&15 (=lr), row = kg*4 + reg, tile row += 16*wv
    __syncthreads();   // staging reads done before qS/kS overwrite
    #pragma unroll
    for (int ni = 0; ni < 4; ++ni) {
        float bqv = bq[h * 64 + ni * 16 + lr];
        float bkv = bk[h * 64 + ni * 16 + lr];
        #pragma unroll
        for (int r = 0; r < 4; ++r) {
            int row = wv * 16 + kg * 4 + r;
            qS[row * LDQ + ni * 16 + lr] = acc_q[ni][r] + bqv;
            kS[row * LDQ + ni * 16 + lr] = acc_k[ni][r] + bkv;
        }
    }
    __syncthreads();

    // export edge rows (0 and 63) for boundary dots in gscan
    const int eb = (rt * 8 + h) * 64;
    if (tid < 64) {
        qF[eb + tid] = qS[tid];
        kF[eb + tid] = kS[tid];
    } else if (tid >= 192) {
        int l = tid - 192;
        qL[eb + l] = qS[63 * LDQ + l];
        kL[eb + l] = kS[63 * LDQ + l];
    }

    // in-tile neighbor dots: wave wv handles p = wv, wv+4, ...
    for (int p = wv; p < 63; p += 4) {
        float pu = qS[p * LDQ + lane] * kS[(p + 1) * LDQ + lane];
        float pv = qS[(p + 1) * LDQ + lane] * kS[p * LDQ + lane];
        #pragma unroll
        for (int m = 1; m < 64; m <<= 1) {
            pu += __shfl_xor(pu, m);
            pv += __shfl_xor(pv, m);
        }
        if (lane == 0) {
            int r = rt * 64 + p;
            int idx = (((r >> 10) * 8 + h) << 10) | (r & 1023);
            uA[idx] = pu * (1.0f / DM);
            vA[idx] = pv * (1.0f / DM);
        }
    }
}

// ---------------------------------------------------------------------------
// Kernel 3: boundary dots + tridiagonal softmax -> g + exclusive log-scan.
// Blocks 0..31 = (b,h), 1024 threads. +1280 bg writer blocks (40 MB).
// ---------------------------------------------------------------------------
__global__ __launch_bounds__(1024) void gscan_kernel(
    const float* __restrict__ uA, const float* __restrict__ vA,
    const float* __restrict__ qF, const float* __restrict__ kF,
    const float* __restrict__ qL, const float* __restrict__ kL,
    const int* __restrict__ am, float* __restrict__ gA, float* __restrict__ CA,
    float* __restrict__ phrasal)
{
    __shared__ float uS[SEQ], vS[SEQ];
    __shared__ float uFix[16], vFix[16];
    __shared__ double wsum[16];

    const int blk = blockIdx.x, i = threadIdx.x;
    if (blk >= 32) {
        bgwrite(phrasal + (size_t)(2816 + blk - 32) * 8192, 2, i, 1024); // 2816..4095
        return;
    }

    const int bh = blk, b = bh >> 3, h = bh & 7;
    const int base = bh * SEQ;
    const int wv = i >> 6, lane = i & 63;

    // stage u,v (boundary slots i%64==63 hold garbage, patched below)
    uS[i] = uA[base + i];
    vS[i] = vA[base + i];

    // boundary dots: wave j<15 computes pair i = 64j+63 (crosses tiles j, j+1)
    if (wv < 15) {
        int e0 = ((b * 16 + wv) * 8 + h) * 64;   // tile rt = b*16+wv
        int e1 = e0 + 8 * 64;                    // tile rt+1
        float pu = qL[e0 + lane] * kF[e1 + lane];
        float pv = qF[e1 + lane] * kL[e0 + lane];
        #pragma unroll
        for (int m = 1; m < 64; m <<= 1) {
            pu += __shfl_xor(pu, m);
            pv += __shfl_xor(pv, m);
        }
        if (lane == 0) { uFix[wv] = pu * (1.0f / DM); vFix[wv] = pv * (1.0f / DM); }
    }
    __syncthreads();
    if ((i & 63) == 63) {
        int j = i >> 6;
        uS[i] = (j < 15) ? uFix[j] : 0.f;   // i==1023: u,v unused, zero for safety
        vS[i] = (j < 15) ? vFix[j] : 0.f;
    }
    __syncthreads();

    // tridiagonal softmax -> g
    float g = 0.f;
    if (i < SEQ - 1) {
        float u = uS[i], vv = vS[i];
        float vm1 = (i > 0) ? vS[i - 1] : 0.f;
        float up1 = uS[i + 1];
        const int* amb = am + b * SEQ;
        int mL = (i > 0) ? amb[i - 1] : 0;
        int mR = amb[i + 1];
        float s_up = mR ? (mL ? 1.f / (1.f + expf(vm1 - u)) : 1.f) : 0.f;
        int mL2 = amb[i];
        int mR2 = (i + 2 < SEQ) ? amb[i + 2] : 0;
        float s_dn = mL2 ? (mR2 ? 1.f / (1.f + expf(up1 - vv)) : 1.f) : 0.f;
        g = sqrtf(s_up * s_dn + EPS);
        gA[base + i] = g;
    }

    // exclusive prefix-sum of log(g+eps), double precision
    double L = (i < SEQ - 1) ? (double)logf(g + EPS) : 0.0;
    double x = L;
    #pragma unroll
    for (int off = 1; off < 64; off <<= 1) {
        double t = __shfl_up(x, off);
        if (lane >= off) x += t;
    }
    if (lane == 63) wsum[wv] = x;
    __syncthreads();
    double pref = 0.0;
    for (int w = 0; w < wv; ++w) pref += wsum[w];
    CA[base + i] = (float)(pref + x - L);
}

// ---------------------------------------------------------------------------
// Kernel 4: attn fill + phrasal off-diagonal fix-up. One block per (bh,i) row.
// ---------------------------------------------------------------------------
__global__ __launch_bounds__(256) void fill_attn(
    const float* __restrict__ gA, const float* __restrict__ CA,
    float* __restrict__ attn, float* __restrict__ phrasal)
{
    const int row = blockIdx.x;           // bh*1024 + i
    const int bh  = row >> 10;
    const int i   = row & 1023;
    const int t   = threadIdx.x;

    const float Ci = CA[row];
    floatx4 c4 = *(const floatx4*)(CA + bh * SEQ + t * 4);
    floatx4 av;
    #pragma unroll
    for (int j = 0; j < 4; ++j) {
        int k = t * 4 + j;
        float d = (k > i) ? (c4[j] - Ci) : (Ci - c4[j]);
        av[j] = (k == i) ? SQRTEPS : (__expf(d) + EPS);
    }
    *(floatx4*)(attn + (size_t)row * SEQ + t * 4) = av;

    if (t == 0 && i > 0)
        phrasal[(size_t)row * SEQ + i - 1] = gA[bh * SEQ + i - 1];
    if (t == 1 && i < SEQ - 1)
        phrasal[(size_t)row * SEQ + i + 1] = gA[bh * SEQ + i];
}

// ---------------------------------------------------------------------------
extern "C" void kernel_launch(void* const* d_in, const int* in_sizes, int n_in,
                              void* d_out, int out_size, void* d_ws, size_t ws_size,
                              hipStream_t stream) {
    const float* ctx = (const float*)d_in[0];
    const int*   am  = (const int*)d_in[1];
    const float* Wq  = (const float*)d_in[2];
    const float* bq  = (const float*)d_in[3];
    const float* Wk  = (const float*)d_in[4];
    const float* bk  = (const float*)d_in[5];
    float* out = (float*)d_out;

    char* ws = (char*)d_ws;
    unsigned short* Xbf = (unsigned short*)(ws);                 //  4 MiB
    unsigned short* Wbf = (unsigned short*)(ws + 4194304);       //  1 MiB
    float*          uA  = (float*)(ws + 5242880);                // 128 KiB
    float*          vA  = (float*)(ws + 5373952);                // 128 KiB
    float*          gA  = (float*)(ws + 5505024);                // 128 KiB
    float*          CA  = (float*)(ws + 5636096);                // 128 KiB
    float*          qF  = (float*)(ws + 5767168);                // 128 KiB edges
    float*          kF  = (float*)(ws + 5898240);
    float*          qL  = (float*)(ws + 6029312);
    float*          kL  = (float*)(ws + 6160384);

    float* attn_out    = out;
    float* phrasal_out = out + (size_t)BS * 8 * SEQ * SEQ;

    convert_kernel<<<dim3(256 + 768), 256, 0, stream>>>(ctx, Wq, Wk, Xbf, Wbf, phrasal_out);
    gemmdot_kernel<<<dim3(NGEMM + 2048), 256, 0, stream>>>(
        Xbf, Wbf, bq, bk, uA, vA, qF, kF, qL, kL, phrasal_out);
    gscan_kernel<<<dim3(32 + 1280), 1024, 0, stream>>>(
        uA, vA, qF, kF, qL, kL, am, gA, CA, phrasal_out);
    fill_attn<<<dim3(BS * 8 * SEQ), 256, 0, stream>>>(gA, CA, attn_out, phrasal_out);
}